// Round 1
// baseline (288.532 us; speedup 1.0000x reference)
//
#include <hip/hip_runtime.h>
#include <hip/hip_bf16.h>
#include <cstdint>

#define B_ 8
#define C_ 256
#define N_ 2304
// per-source xT bytes: 8 * 2304 * 256 * 2
#define XT_BYTES ((size_t)B_ * N_ * C_ * 2)
#define QK_BYTES ((size_t)16 * N_ * C_ * 2)
#define V_BYTES  ((size_t)16 * C_ * N_ * 2)

typedef __bf16 bf16x8 __attribute__((ext_vector_type(8)));
typedef float  f32x4  __attribute__((ext_vector_type(4)));
static_assert(sizeof(bf16x8) == 16, "");

// ---------------------------------------------------------------------------
// Kernel 1: transpose + cvt: x[b][i][n] f32 -> xT[b][n][i] bf16, swizzled rows
// row byte layout: byte(c) = (c*2) ^ ((n&7)<<4)   (rows are 512B)
// ---------------------------------------------------------------------------
__global__ __launch_bounds__(256) void k_transpose(
    const float* __restrict__ rgb, const float* __restrict__ tin,
    char* __restrict__ xT)
{
  const int nt = blockIdx.x;   // 36 n-tiles of 64
  const int it = blockIdx.y;   // 4 i-tiles of 64
  const int z  = blockIdx.z;   // src*8 + b
  const int src = z >> 3, b = z & 7;
  const float* __restrict__ in = (src ? tin : rgb) + (size_t)b * C_ * N_;
  char* __restrict__ out = xT + (size_t)src * XT_BYTES + (size_t)b * N_ * 512;
  const int i0 = it * 64, n0 = nt * 64;
  __shared__ float raw[64 * 65];
  const int t = threadIdx.x;
  const int rr = t >> 4;       // 0..15
  const int cc = t & 15;
#pragma unroll
  for (int j = 0; j < 4; ++j) {
    const int ii = rr + 16 * j;
    const float4 v = *(const float4*)(in + (size_t)(i0 + ii) * N_ + n0 + cc * 4);
    float* rp = &raw[ii * 65 + cc * 4];
    rp[0] = v.x; rp[1] = v.y; rp[2] = v.z; rp[3] = v.w;
  }
  __syncthreads();
#pragma unroll
  for (int k = 0; k < 4; ++k) {
    const int nl = rr + 16 * k;
    const int n = n0 + nl;
    union { __bf16 h[4]; uint2 u; } pk;
#pragma unroll
    for (int e = 0; e < 4; ++e)
      pk.h[e] = (__bf16)raw[(cc * 4 + e) * 65 + nl];
    const int cb = ((i0 + cc * 4) * 2) ^ ((n & 7) << 4);
    *(uint2*)(out + (size_t)n * 512 + cb) = pk.u;
  }
}

// ---------------------------------------------------------------------------
// Kernel 2: weights f32 -> bf16 swizzled rows (order wq1,wk1,wq2,wk2,wv1,wv2)
// ---------------------------------------------------------------------------
__global__ __launch_bounds__(256) void k_wcvt(
    const float* __restrict__ w0, const float* __restrict__ w1,
    const float* __restrict__ w2, const float* __restrict__ w3,
    const float* __restrict__ w4, const float* __restrict__ w5,
    char* __restrict__ Wb)
{
  const int widx = blockIdx.y;
  const float* w = widx == 0 ? w0 : widx == 1 ? w1 : widx == 2 ? w2
                 : widx == 3 ? w3 : widx == 4 ? w4 : w5;
  const int t = threadIdx.x;
  const int row = blockIdx.x * 8 + (t >> 5);
  const int c8 = (t & 31) * 8;
  const float4 v0 = *(const float4*)(w + row * 256 + c8);
  const float4 v1 = *(const float4*)(w + row * 256 + c8 + 4);
  union { __bf16 h[8]; uint4 u; } pk;
  pk.h[0] = (__bf16)v0.x; pk.h[1] = (__bf16)v0.y; pk.h[2] = (__bf16)v0.z; pk.h[3] = (__bf16)v0.w;
  pk.h[4] = (__bf16)v1.x; pk.h[5] = (__bf16)v1.y; pk.h[6] = (__bf16)v1.z; pk.h[7] = (__bf16)v1.w;
  const int cb = (c8 * 2) ^ ((row & 7) << 4);
  *(uint4*)(Wb + (size_t)(widx * 256 + row) * 512 + cb) = pk.u;
}

// ---------------------------------------------------------------------------
// Kernel 3: Q/K projection. out[n][o] = sum_i xT[n][i]*w[o][i] + bias[o]
// z: 0=q1(rgb) 1=k1(t) 2=q2(t) 3=k2(rgb). Tile 128n x 64o, BK=64, 4 waves 2x2.
// ---------------------------------------------------------------------------
__global__ __launch_bounds__(256, 2) void k_proj_qk(
    const char* __restrict__ xT, const char* __restrict__ Wb,
    const float* __restrict__ bq1, const float* __restrict__ bk1,
    const float* __restrict__ bq2, const float* __restrict__ bk2,
    char* __restrict__ Qw, char* __restrict__ Kw)
{
  const int z = blockIdx.z;
  const int b = blockIdx.y;
  const int ntile = blockIdx.x >> 2, otile = blockIdx.x & 3;
  const int n0 = ntile * 128, o0 = otile * 64;
  const int srcT = (z == 1 || z == 2);
  const char* __restrict__ xp = xT + (size_t)srcT * XT_BYTES + (size_t)b * N_ * 512;
  const char* __restrict__ Wp = Wb + (size_t)z * C_ * 512;
  const float* __restrict__ bias = z == 0 ? bq1 : z == 1 ? bk1 : z == 2 ? bq2 : bk2;
  char* __restrict__ outp = ((z == 0 || z == 2) ? Qw : Kw)
                            + (size_t)((z >= 2 ? 8 : 0) + b) * N_ * 512;

  __shared__ alignas(16) char Alds[128 * 128];
  __shared__ alignas(16) char Wlds[64 * 128];
  const int t = threadIdx.x, lane = t & 63, wid = t >> 6;
  const int wm = wid >> 1, wn = wid & 1;
  const int lr = lane & 15, lk = lane >> 4;
  f32x4 acc[4][2] = {};

  for (int ko = 0; ko < 4; ++ko) {
    const int ib = ko * 128;
    __syncthreads();
#pragma unroll
    for (int s = 0; s < 4; ++s) {
      const int flat = s * 4096 + t * 16;
      *(uint4*)(Alds + flat) =
          *(const uint4*)(xp + (size_t)(n0 + (flat >> 7)) * 512 + ib + (flat & 127));
    }
#pragma unroll
    for (int s = 0; s < 2; ++s) {
      const int flat = s * 4096 + t * 16;
      *(uint4*)(Wlds + flat) =
          *(const uint4*)(Wp + (size_t)(o0 + (flat >> 7)) * 512 + ib + (flat & 127));
    }
    __syncthreads();
#pragma unroll
    for (int ks = 0; ks < 2; ++ks) {
      bf16x8 af[4], bfr[2];
#pragma unroll
      for (int mf = 0; mf < 4; ++mf) {
        const int row = wm * 64 + mf * 16 + lr;
        af[mf] = *(const bf16x8*)(Alds + row * 128 + ((ks * 64 + lk * 16) ^ ((row & 7) << 4)));
      }
#pragma unroll
      for (int nf = 0; nf < 2; ++nf) {
        const int row = wn * 32 + nf * 16 + lr;
        bfr[nf] = *(const bf16x8*)(Wlds + row * 128 + ((ks * 64 + lk * 16) ^ ((row & 7) << 4)));
      }
#pragma unroll
      for (int mf = 0; mf < 4; ++mf)
#pragma unroll
        for (int nf = 0; nf < 2; ++nf)
          acc[mf][nf] = __builtin_amdgcn_mfma_f32_16x16x32_bf16(af[mf], bfr[nf], acc[mf][nf], 0, 0, 0);
    }
  }
#pragma unroll
  for (int nf = 0; nf < 2; ++nf) {
    const int c = o0 + wn * 32 + nf * 16 + lr;
    const float bv = bias[c];
#pragma unroll
    for (int mf = 0; mf < 4; ++mf)
#pragma unroll
      for (int r = 0; r < 4; ++r) {
        const int n = n0 + wm * 64 + mf * 16 + lk * 4 + r;
        *(__bf16*)(outp + (size_t)n * 512 + ((c * 2) ^ ((n & 7) << 4))) =
            (__bf16)(acc[mf][nf][r] + bv);
      }
  }
}

// ---------------------------------------------------------------------------
// Kernel 4: V projection, stored transposed: out[o][n] = sum_i w[o][i]*xT[n][i] + bias[o]
// z: 0=v1(t) 1=v2(rgb). Tile 64o x 128n, 4 waves 2x2 (wave = 32o x 64n).
// V rows are 4608B, swizzle byte(n) = (n*2) ^ ((o&7)<<4)
// ---------------------------------------------------------------------------
__global__ __launch_bounds__(256, 2) void k_proj_v(
    const char* __restrict__ xT, const char* __restrict__ Wb,
    const float* __restrict__ bv1, const float* __restrict__ bv2,
    char* __restrict__ Vw)
{
  const int z = blockIdx.z;
  const int b = blockIdx.y;
  const int ntile = blockIdx.x >> 2, otile = blockIdx.x & 3;
  const int n0 = ntile * 128, o0 = otile * 64;
  const char* __restrict__ xp = xT + (size_t)(z == 0 ? 1 : 0) * XT_BYTES + (size_t)b * N_ * 512;
  const char* __restrict__ Wp = Wb + (size_t)(4 + z) * C_ * 512;
  const float* __restrict__ bias = z ? bv2 : bv1;
  char* __restrict__ outp = Vw + (size_t)(z * 8 + b) * C_ * 4608;

  __shared__ alignas(16) char Xlds[128 * 128];
  __shared__ alignas(16) char Wlds[64 * 128];
  const int t = threadIdx.x, lane = t & 63, wid = t >> 6;
  const int wm = wid >> 1, wn = wid & 1;
  const int lr = lane & 15, lk = lane >> 4;
  f32x4 acc[2][4] = {};

  for (int ko = 0; ko < 4; ++ko) {
    const int ib = ko * 128;
    __syncthreads();
#pragma unroll
    for (int s = 0; s < 4; ++s) {
      const int flat = s * 4096 + t * 16;
      *(uint4*)(Xlds + flat) =
          *(const uint4*)(xp + (size_t)(n0 + (flat >> 7)) * 512 + ib + (flat & 127));
    }
#pragma unroll
    for (int s = 0; s < 2; ++s) {
      const int flat = s * 4096 + t * 16;
      *(uint4*)(Wlds + flat) =
          *(const uint4*)(Wp + (size_t)(o0 + (flat >> 7)) * 512 + ib + (flat & 127));
    }
    __syncthreads();
#pragma unroll
    for (int ks = 0; ks < 2; ++ks) {
      bf16x8 af[2], bfr[4];
#pragma unroll
      for (int mf = 0; mf < 2; ++mf) {
        const int row = wm * 32 + mf * 16 + lr;
        af[mf] = *(const bf16x8*)(Wlds + row * 128 + ((ks * 64 + lk * 16) ^ ((row & 7) << 4)));
      }
#pragma unroll
      for (int nf = 0; nf < 4; ++nf) {
        const int row = wn * 64 + nf * 16 + lr;
        bfr[nf] = *(const bf16x8*)(Xlds + row * 128 + ((ks * 64 + lk * 16) ^ ((row & 7) << 4)));
      }
#pragma unroll
      for (int mf = 0; mf < 2; ++mf)
#pragma unroll
        for (int nf = 0; nf < 4; ++nf)
          acc[mf][nf] = __builtin_amdgcn_mfma_f32_16x16x32_bf16(af[mf], bfr[nf], acc[mf][nf], 0, 0, 0);
    }
  }
#pragma unroll
  for (int mf = 0; mf < 2; ++mf)
#pragma unroll
    for (int r = 0; r < 4; ++r) {
      const int o = o0 + wm * 32 + mf * 16 + lk * 4 + r;
      const float bv = bias[o];
#pragma unroll
      for (int nf = 0; nf < 4; ++nf) {
        const int n = n0 + wn * 64 + nf * 16 + lr;
        *(__bf16*)(outp + (size_t)o * 4608 + ((n * 2) ^ ((o & 7) << 4))) =
            (__bf16)(acc[mf][nf][r] + bv);
      }
    }
}

// ---------------------------------------------------------------------------
// Kernel 5: flash attention + residuals + transpose-write.
// Block = 4 waves, 64 Q-rows (16/wave). KV tile 64. Q in registers.
// out[a][b][c][n] = x[c][n] + q[n][c] + (P@V)[n][c]/l[n]
// ---------------------------------------------------------------------------
__global__ __launch_bounds__(256, 2) void k_flash(
    const char* __restrict__ Qw, const char* __restrict__ Kw, const char* __restrict__ Vw,
    const float* __restrict__ rgb, const float* __restrict__ tin,
    float* __restrict__ outp)
{
  const int qt = blockIdx.x;    // 36
  const int pair = blockIdx.y;  // 16
  const int a = pair >> 3, b = pair & 7;
  const char* __restrict__ Qp = Qw + (size_t)pair * N_ * 512;
  const char* __restrict__ Kp = Kw + (size_t)pair * N_ * 512;
  const char* __restrict__ Vp = Vw + (size_t)pair * C_ * 4608;
  const float* __restrict__ xsrc = (a ? tin : rgb) + (size_t)b * C_ * N_;
  float* __restrict__ op = outp + (size_t)(a * 8 + b) * C_ * N_;

  __shared__ alignas(16) char Klds[64 * 512];
  __shared__ alignas(16) char Vlds[256 * 128];
  __shared__ alignas(16) char Plds[4 * 2048];

  const int t = threadIdx.x, lane = t & 63, w = t >> 6;
  const int lr = lane & 15, lk = lane >> 4;
  const int q0 = qt * 64;

  // Q fragments: 16 rows per wave, held in registers for the whole kernel
  bf16x8 qf[8];
  {
    const int n = q0 + w * 16 + lr;
    const char* qrow = Qp + (size_t)n * 512;
    const int sw = (n & 7) << 4;
#pragma unroll
    for (int ks = 0; ks < 8; ++ks)
      qf[ks] = *(const bf16x8*)(qrow + ((ks * 64 + lk * 16) ^ sw));
  }

  f32x4 oacc[16] = {};
  float m_run[4], l_run[4];
#pragma unroll
  for (int r = 0; r < 4; ++r) { m_run[r] = -1e30f; l_run[r] = 0.f; }

  for (int kv = 0; kv < 36; ++kv) {
    const size_t kb = (size_t)kv * 64;
    {
      const char* Ksrc = Kp + kb * 512;   // K tile is fully contiguous
#pragma unroll
      for (int s = 0; s < 8; ++s) {
        const int flat = s * 4096 + t * 16;
        *(uint4*)(Klds + flat) = *(const uint4*)(Ksrc + flat);
      }
      const char* Vsrc = Vp + kb * 2;     // 128B segment per V row
#pragma unroll
      for (int s = 0; s < 8; ++s) {
        const int flat = s * 4096 + t * 16;
        *(uint4*)(Vlds + flat) =
            *(const uint4*)(Vsrc + (size_t)(flat >> 7) * 4608 + (flat & 127));
      }
    }
    __syncthreads();

    // S = Q K^T  (wave's 16 rows x 64 kv cols)
    f32x4 s4[4] = {};
#pragma unroll
    for (int mf = 0; mf < 4; ++mf) {
      const int row = mf * 16 + lr;
      const char* kr = Klds + row * 512;
      const int sw = (row & 7) << 4;
#pragma unroll
      for (int ks = 0; ks < 8; ++ks) {
        const bf16x8 kf = *(const bf16x8*)(kr + ((ks * 64 + lk * 16) ^ sw));
        s4[mf] = __builtin_amdgcn_mfma_f32_16x16x32_bf16(qf[ks], kf, s4[mf], 0, 0, 0);
      }
    }

    // online softmax (rows owned per r within 16-lane groups)
    float scale[4];
#pragma unroll
    for (int r = 0; r < 4; ++r) {
      float m0 = fmaxf(fmaxf(s4[0][r], s4[1][r]), fmaxf(s4[2][r], s4[3][r]));
      m0 = fmaxf(m0, __shfl_xor(m0, 1));
      m0 = fmaxf(m0, __shfl_xor(m0, 2));
      m0 = fmaxf(m0, __shfl_xor(m0, 4));
      m0 = fmaxf(m0, __shfl_xor(m0, 8));
      const float mn = fmaxf(m_run[r], m0);
      scale[r] = __expf(m_run[r] - mn);
      m_run[r] = mn;
    }

    float psum[4] = {0.f, 0.f, 0.f, 0.f};
    char* pw = Plds + w * 2048;
#pragma unroll
    for (int mf = 0; mf < 4; ++mf)
#pragma unroll
      for (int r = 0; r < 4; ++r) {
        const float p = __expf(s4[mf][r] - m_run[r]);
        psum[r] += p;
        const int row = lk * 4 + r;
        const int col = mf * 16 + lr;
        *(__bf16*)(pw + row * 128 + ((col * 2) ^ ((row & 7) << 4))) = (__bf16)p;
      }
#pragma unroll
    for (int r = 0; r < 4; ++r) {
      float s0 = psum[r];
      s0 += __shfl_xor(s0, 1);
      s0 += __shfl_xor(s0, 2);
      s0 += __shfl_xor(s0, 4);
      s0 += __shfl_xor(s0, 8);
      l_run[r] = l_run[r] * scale[r] + s0;
    }
#pragma unroll
    for (int cf = 0; cf < 16; ++cf)
#pragma unroll
      for (int r = 0; r < 4; ++r) oacc[cf][r] *= scale[r];

    // O += P @ V   (P read back in A-frag layout; same-wave LDS ordering)
#pragma unroll
    for (int ks2 = 0; ks2 < 2; ++ks2) {
      const bf16x8 pf =
          *(const bf16x8*)(pw + lr * 128 + ((ks2 * 64 + lk * 16) ^ ((lr & 7) << 4)));
#pragma unroll
      for (int cf = 0; cf < 16; ++cf) {
        const int vr = cf * 16 + lr;
        const bf16x8 vf =
            *(const bf16x8*)(Vlds + vr * 128 + ((ks2 * 64 + lk * 16) ^ ((vr & 7) << 4)));
        oacc[cf] = __builtin_amdgcn_mfma_f32_16x16x32_bf16(pf, vf, oacc[cf], 0, 0, 0);
      }
    }
    __syncthreads();
  }

  // epilogue: out[c][n] = x[c][n] + q[n][c] + O[n][c]/l
  float inv[4];
#pragma unroll
  for (int r = 0; r < 4; ++r) inv[r] = 1.0f / l_run[r];
  const int nb = q0 + w * 16 + lk * 4;
#pragma unroll
  for (int cf = 0; cf < 16; ++cf) {
    const int c = cf * 16 + lr;
    const float4 xv = *(const float4*)(xsrc + (size_t)c * N_ + nb);
    float vals[4];
#pragma unroll
    for (int r = 0; r < 4; ++r) {
      const int n = nb + r;
      const float qv =
          (float)(*(const __bf16*)(Qp + (size_t)n * 512 + ((c * 2) ^ ((n & 7) << 4))));
      vals[r] = oacc[cf][r] * inv[r] + qv;
    }
    float4 ov;
    ov.x = vals[0] + xv.x; ov.y = vals[1] + xv.y;
    ov.z = vals[2] + xv.z; ov.w = vals[3] + xv.w;
    *(float4*)(op + (size_t)c * N_ + nb) = ov;
  }
}

// ---------------------------------------------------------------------------
extern "C" void kernel_launch(void* const* d_in, const int* in_sizes, int n_in,
                              void* d_out, int out_size, void* d_ws, size_t ws_size,
                              hipStream_t stream) {
  const float* rgb = (const float*)d_in[0];
  const float* tin = (const float*)d_in[1];
  const float* wq1 = (const float*)d_in[2];
  const float* bq1 = (const float*)d_in[3];
  const float* wk1 = (const float*)d_in[4];
  const float* bk1 = (const float*)d_in[5];
  const float* wv1 = (const float*)d_in[6];
  const float* bv1 = (const float*)d_in[7];
  const float* wq2 = (const float*)d_in[8];
  const float* bq2 = (const float*)d_in[9];
  const float* wk2 = (const float*)d_in[10];
  const float* bk2 = (const float*)d_in[11];
  const float* wv2 = (const float*)d_in[12];
  const float* bv2 = (const float*)d_in[13];

  char* ws = (char*)d_ws;
  char* xT = ws;                       // 2 * 9,437,184
  char* Qw = ws + 2 * XT_BYTES;        // 18,874,368
  char* Kw = Qw + QK_BYTES;            // 18,874,368
  char* Vw = Kw + QK_BYTES;            // 18,874,368
  char* Wb = Vw + V_BYTES;             // 786,432   (total ~76.3 MB)

  k_transpose<<<dim3(36, 4, 16), 256, 0, stream>>>(rgb, tin, xT);
  k_wcvt<<<dim3(32, 6), 256, 0, stream>>>(wq1, wk1, wq2, wk2, wv1, wv2, Wb);
  k_proj_qk<<<dim3(72, 8, 4), 256, 0, stream>>>(xT, Wb, bq1, bk1, bq2, bk2, Qw, Kw);
  k_proj_v<<<dim3(72, 8, 2), 256, 0, stream>>>(xT, Wb, bv1, bv2, Vw);
  k_flash<<<dim3(36, 16), 256, 0, stream>>>(Qw, Kw, Vw, rgb, tin, (float*)d_out);
}